// Round 1
// baseline (279.325 us; speedup 1.0000x reference)
//
#include <hip/hip_runtime.h>
#include <math.h>

#define EMBED   128
#define NHEADS  8
#define NPOINTS 4
#define HD      16
#define HSP     51
#define WSP     102
#define NPIX    (HSP * WSP)   // 5202
#define NQ      10000
#define NLVL    50

// ---------------------------------------------------------------------------
// Kernel 1: value projection  v = value @ W_val + b_val, stored per-head:
// vout[((h*NPIX + pix)*HD + c)]  (so [h][pix][c0..15] is float4-loadable)
// ---------------------------------------------------------------------------
__global__ void k_valproj(const float* __restrict__ value,
                          const float* __restrict__ Wv,
                          const float* __restrict__ bv,
                          float* __restrict__ vout) {
    __shared__ float vrow[EMBED];
    const int pix = blockIdx.x;
    const int t = threadIdx.x;
    vrow[t] = value[(size_t)pix * EMBED + t];
    __syncthreads();
    float acc = bv[t];
#pragma unroll 8
    for (int k = 0; k < EMBED; ++k)
        acc = fmaf(vrow[k], Wv[(size_t)k * EMBED + t], acc);
    const int h = t >> 4, c = t & 15;
    vout[((size_t)h * NPIX + pix) * HD + c] = acc;
}

// ---------------------------------------------------------------------------
// Kernel 2: per-query sampling offsets (64) and softmaxed attention (32)
// ---------------------------------------------------------------------------
__global__ void k_offattn(const float* __restrict__ query,
                          const float* __restrict__ Woff,
                          const float* __restrict__ boff,
                          const float* __restrict__ Wattn,
                          const float* __restrict__ battn,
                          float* __restrict__ off_out,
                          float* __restrict__ aw_out) {
    __shared__ float qrow[EMBED];
    __shared__ float attn[32];
    const int q = blockIdx.x;
    const int t = threadIdx.x;
    qrow[t] = query[(size_t)q * EMBED + t];
    __syncthreads();
    if (t < 64) {
        float acc = boff[t];
#pragma unroll 8
        for (int k = 0; k < EMBED; ++k)
            acc = fmaf(qrow[k], Woff[(size_t)k * 64 + t], acc);
        off_out[(size_t)q * 64 + t] = acc;
    } else if (t < 96) {
        const int j = t - 64;
        float acc = battn[j];
#pragma unroll 8
        for (int k = 0; k < EMBED; ++k)
            acc = fmaf(qrow[k], Wattn[(size_t)k * 32 + j], acc);
        attn[j] = acc;
    }
    __syncthreads();
    if (t < NHEADS) {
        const float a0 = attn[t * 4 + 0], a1 = attn[t * 4 + 1];
        const float a2 = attn[t * 4 + 2], a3 = attn[t * 4 + 3];
        const float mx = fmaxf(fmaxf(a0, a1), fmaxf(a2, a3));
        const float e0 = __expf(a0 - mx), e1 = __expf(a1 - mx);
        const float e2 = __expf(a2 - mx), e3 = __expf(a3 - mx);
        const float inv = 1.f / (e0 + e1 + e2 + e3);
        aw_out[(size_t)q * 32 + t * 4 + 0] = e0 * inv;
        aw_out[(size_t)q * 32 + t * 4 + 1] = e1 * inv;
        aw_out[(size_t)q * 32 + t * 4 + 2] = e2 * inv;
        aw_out[(size_t)q * 32 + t * 4 + 3] = e3 * inv;
    }
}

// ---------------------------------------------------------------------------
// Kernel 3: u = W_out @ W_proj  (128 floats). b_proj / b_out / query terms are
// level-constant -> drop out of softmax and argmax (shift invariance).
// ---------------------------------------------------------------------------
__global__ void k_uvec(const float* __restrict__ Wout,
                       const float* __restrict__ Wproj,
                       float* __restrict__ u) {
    const int c = threadIdx.x;
    float acc = 0.f;
#pragma unroll 8
    for (int d = 0; d < EMBED; ++d)
        acc = fmaf(Wout[(size_t)c * EMBED + d], Wproj[d], acc);
    u[c] = acc;
}

// ---------------------------------------------------------------------------
// Kernel 4: main. 32 lanes per query: lane = h*4 + c4 (h in [0,8), c4 in [0,4))
// owning channels h*16 + c4*4 .. +3. 2 queries per wave, 8 per 256-thread block.
// Online softmax over 50 levels; fused final matvec s @ W_out + b_out + 2q.
// ---------------------------------------------------------------------------
__global__ __launch_bounds__(256) void k_main(
    const float* __restrict__ query,
    const float* __restrict__ refp,   // (NLVL, NQ, 2)
    const float* __restrict__ voff,   // (NQ, 8, 4, 2)
    const float* __restrict__ vaw,    // (NQ, 8, 4)
    const float* __restrict__ vflat,  // (8, NPIX, 16)
    const float* __restrict__ uvec,   // (128)
    const float* __restrict__ Wout,   // (128, 128)
    const float* __restrict__ bout,   // (128)
    float* __restrict__ out0,         // (NQ, 128)
    float* __restrict__ out1) {       // (NQ) argmax level, stored as float
    const int t = threadIdx.x;
    const int sub = t & 31;           // lane within query group
    const int slot = t >> 5;          // query slot in block (0..7)
    const int q = blockIdx.x * 8 + slot;
    const int h = sub >> 2;
    const int c4 = sub & 3;

    __shared__ float4 s_lds[8][32];

    const float4* offp = (const float4*)(voff + (size_t)q * 64 + h * 8);
    const float4 o01 = offp[0];       // p0.x p0.y p1.x p1.y
    const float4 o23 = offp[1];
    const float4 awv4 = *(const float4*)(vaw + (size_t)q * 32 + h * 4);
    const float4 u4 = *(const float4*)(uvec + h * 16 + c4 * 4);
    // float4 index for (h, pix, c4): (h*NPIX + pix)*4 + c4
    const float4* vbase = (const float4*)vflat + (size_t)h * NPIX * 4 + c4;

    const float offx[4] = {o01.x, o01.z, o23.x, o23.z};
    const float offy[4] = {o01.y, o01.w, o23.y, o23.w};
    const float awv[4]  = {awv4.x, awv4.y, awv4.z, awv4.w};

    float4 acc = {0.f, 0.f, 0.f, 0.f};
    float m = -1e30f, Z = 0.f;
    int best = 0;

    for (int l = 0; l < NLVL; ++l) {
        const float2 rp = *(const float2*)(refp + ((size_t)l * NQ + q) * 2);
        float4 s = {0.f, 0.f, 0.f, 0.f};
#pragma unroll
        for (int p = 0; p < NPOINTS; ++p) {
            // px = (ref.x + off.x/WSP)*WSP - 0.5 = ref.x*WSP + off.x - 0.5
            const float px = fmaf(rp.x, (float)WSP, offx[p]) - 0.5f;
            const float py = fmaf(rp.y, (float)HSP, offy[p]) - 0.5f;
            const float fx = floorf(px), fy = floorf(py);
            const float dx = px - fx, dy = py - fy;
            const int x0 = (int)fx, y0 = (int)fy;
            const float a = awv[p];
            float w00 = a * (1.f - dx) * (1.f - dy);
            float w01 = a * dx * (1.f - dy);
            float w10 = a * (1.f - dx) * dy;
            float w11 = a * dx * dy;
            const bool vx0 = (x0 >= 0) && (x0 < WSP);
            const bool vx1 = (x0 >= -1) && (x0 < WSP - 1);
            const bool vy0 = (y0 >= 0) && (y0 < HSP);
            const bool vy1 = (y0 >= -1) && (y0 < HSP - 1);
            w00 = (vx0 && vy0) ? w00 : 0.f;
            w01 = (vx1 && vy0) ? w01 : 0.f;
            w10 = (vx0 && vy1) ? w10 : 0.f;
            w11 = (vx1 && vy1) ? w11 : 0.f;
            const int xc0 = min(max(x0, 0), WSP - 1);
            const int xc1 = min(max(x0 + 1, 0), WSP - 1);
            const int yc0 = min(max(y0, 0), HSP - 1);
            const int yc1 = min(max(y0 + 1, 0), HSP - 1);
            const int i00 = yc0 * WSP + xc0;
            const int i01 = yc0 * WSP + xc1;
            const int i10 = yc1 * WSP + xc0;
            const int i11 = yc1 * WSP + xc1;
            const float4 v00 = vbase[(size_t)i00 * 4];
            const float4 v01 = vbase[(size_t)i01 * 4];
            const float4 v10 = vbase[(size_t)i10 * 4];
            const float4 v11 = vbase[(size_t)i11 * 4];
            s.x = fmaf(w00, v00.x, s.x); s.y = fmaf(w00, v00.y, s.y);
            s.z = fmaf(w00, v00.z, s.z); s.w = fmaf(w00, v00.w, s.w);
            s.x = fmaf(w01, v01.x, s.x); s.y = fmaf(w01, v01.y, s.y);
            s.z = fmaf(w01, v01.z, s.z); s.w = fmaf(w01, v01.w, s.w);
            s.x = fmaf(w10, v10.x, s.x); s.y = fmaf(w10, v10.y, s.y);
            s.z = fmaf(w10, v10.z, s.z); s.w = fmaf(w10, v10.w, s.w);
            s.x = fmaf(w11, v11.x, s.x); s.y = fmaf(w11, v11.y, s.y);
            s.z = fmaf(w11, v11.z, s.z); s.w = fmaf(w11, v11.w, s.w);
        }
        // logit_l = samp_agg . u   (reduce across the 32 lanes of this query)
        float part = s.x * u4.x + s.y * u4.y + s.z * u4.z + s.w * u4.w;
#pragma unroll
        for (int d = 1; d < 32; d <<= 1)
            part += __shfl_xor(part, d, 64);
        // online softmax + argmax (strict > keeps first occurrence, matching jnp)
        if (part > m) {
            const float sc = __expf(m - part);
            Z = fmaf(Z, sc, 1.f);
            acc.x = fmaf(acc.x, sc, s.x);
            acc.y = fmaf(acc.y, sc, s.y);
            acc.z = fmaf(acc.z, sc, s.z);
            acc.w = fmaf(acc.w, sc, s.w);
            m = part; best = l;
        } else {
            const float w = __expf(part - m);
            Z += w;
            acc.x = fmaf(w, s.x, acc.x);
            acc.y = fmaf(w, s.y, acc.y);
            acc.z = fmaf(w, s.z, acc.z);
            acc.w = fmaf(w, s.w, acc.w);
        }
    }
    const float inv = 1.f / Z;
    float4 sv;
    sv.x = acc.x * inv; sv.y = acc.y * inv; sv.z = acc.z * inv; sv.w = acc.w * inv;
    s_lds[slot][sub] = sv;   // channel-group index == sub (since cbase = sub*4)
    __syncthreads();

    // final: out[dp] = sum_c s[c]*Wout[c][dp] + bout[dp] + 2*query[q][dp]
    const int dpb = sub * 4;
    const float4 b4 = *(const float4*)(bout + dpb);
    const float4 q4 = *(const float4*)(query + (size_t)q * EMBED + dpb);
    float4 r;
    r.x = fmaf(2.f, q4.x, b4.x);
    r.y = fmaf(2.f, q4.y, b4.y);
    r.z = fmaf(2.f, q4.z, b4.z);
    r.w = fmaf(2.f, q4.w, b4.w);
    const float4* srow = s_lds[slot];
#pragma unroll 4
    for (int cg = 0; cg < 32; ++cg) {
        const float4 s4 = srow[cg];
        const float4 w0 = *(const float4*)(Wout + (size_t)(cg * 4 + 0) * EMBED + dpb);
        const float4 w1 = *(const float4*)(Wout + (size_t)(cg * 4 + 1) * EMBED + dpb);
        const float4 w2 = *(const float4*)(Wout + (size_t)(cg * 4 + 2) * EMBED + dpb);
        const float4 w3 = *(const float4*)(Wout + (size_t)(cg * 4 + 3) * EMBED + dpb);
        r.x = fmaf(s4.x, w0.x, r.x); r.y = fmaf(s4.x, w0.y, r.y);
        r.z = fmaf(s4.x, w0.z, r.z); r.w = fmaf(s4.x, w0.w, r.w);
        r.x = fmaf(s4.y, w1.x, r.x); r.y = fmaf(s4.y, w1.y, r.y);
        r.z = fmaf(s4.y, w1.z, r.z); r.w = fmaf(s4.y, w1.w, r.w);
        r.x = fmaf(s4.z, w2.x, r.x); r.y = fmaf(s4.z, w2.y, r.y);
        r.z = fmaf(s4.z, w2.z, r.z); r.w = fmaf(s4.z, w2.w, r.w);
        r.x = fmaf(s4.w, w3.x, r.x); r.y = fmaf(s4.w, w3.y, r.y);
        r.z = fmaf(s4.w, w3.z, r.z); r.w = fmaf(s4.w, w3.w, r.w);
    }
    *(float4*)(out0 + (size_t)q * EMBED + dpb) = r;
    if (sub == 0) out1[q] = (float)best;
}

// ---------------------------------------------------------------------------
extern "C" void kernel_launch(void* const* d_in, const int* in_sizes, int n_in,
                              void* d_out, int out_size, void* d_ws, size_t ws_size,
                              hipStream_t stream) {
    const float* query = (const float*)d_in[0];
    const float* value = (const float*)d_in[1];
    const float* refp  = (const float*)d_in[2];
    const float* Woff  = (const float*)d_in[3];
    const float* boff  = (const float*)d_in[4];
    const float* Wattn = (const float*)d_in[5];
    const float* battn = (const float*)d_in[6];
    const float* Wval  = (const float*)d_in[7];
    const float* bval  = (const float*)d_in[8];
    const float* Wout  = (const float*)d_in[9];
    const float* bout  = (const float*)d_in[10];
    const float* Wproj = (const float*)d_in[11];
    // d_in[12] = b_proj: level-constant -> cancels in softmax/argmax, unused.

    float* ws = (float*)d_ws;
    float* ws_v   = ws;                                   // 8*5202*16 = 665856
    float* ws_off = ws_v + (size_t)NHEADS * NPIX * HD;    // 640000
    float* ws_aw  = ws_off + (size_t)NQ * 64;             // 320000
    float* ws_u   = ws_aw + (size_t)NQ * 32;              // 128

    float* out0 = (float*)d_out;
    float* out1 = out0 + (size_t)NQ * EMBED;

    hipLaunchKernelGGL(k_valproj, dim3(NPIX), dim3(EMBED), 0, stream,
                       value, Wval, bval, ws_v);
    hipLaunchKernelGGL(k_offattn, dim3(NQ), dim3(EMBED), 0, stream,
                       query, Woff, boff, Wattn, battn, ws_off, ws_aw);
    hipLaunchKernelGGL(k_uvec, dim3(1), dim3(EMBED), 0, stream, Wout, Wproj, ws_u);
    hipLaunchKernelGGL(k_main, dim3(NQ / 8), dim3(256), 0, stream,
                       query, refp, ws_off, ws_aw, ws_v, ws_u, Wout, bout,
                       out0, out1);
}

// Round 2
// 253.615 us; speedup vs baseline: 1.1014x; 1.1014x over previous
//
#include <hip/hip_runtime.h>
#include <math.h>

#define EMBED   128
#define NHEADS  8
#define NPOINTS 4
#define HD      16
#define HSP     51
#define WSP     102
#define NPIX    (HSP * WSP)   // 5202
#define NQ      10000
#define NLVL    50

// ---------------------------------------------------------------------------
// Fused prep kernel (one dispatch, blocks branch on role):
//   blocks [0, NPIX)            : value projection -> per-head layout
//   blocks [NPIX, NPIX+NQ)      : per-query offsets + softmaxed attention
//   block  NPIX+NQ              : u = W_out @ W_proj
// ---------------------------------------------------------------------------
__global__ __launch_bounds__(128) void k_prep(
    const float* __restrict__ value,
    const float* __restrict__ Wv,
    const float* __restrict__ bv,
    const float* __restrict__ query,
    const float* __restrict__ Woff,
    const float* __restrict__ boff,
    const float* __restrict__ Wattn,
    const float* __restrict__ battn,
    const float* __restrict__ Wout,
    const float* __restrict__ Wproj,
    float* __restrict__ vout,
    float* __restrict__ off_out,
    float* __restrict__ aw_out,
    float* __restrict__ u_out) {
    const int b = blockIdx.x;
    const int t = threadIdx.x;

    if (b < NPIX) {  // ---- value projection ----
        __shared__ float vrow[EMBED];
        vrow[t] = value[(size_t)b * EMBED + t];
        __syncthreads();
        float acc = bv[t];
#pragma unroll 8
        for (int k = 0; k < EMBED; ++k)
            acc = fmaf(vrow[k], Wv[(size_t)k * EMBED + t], acc);
        const int h = t >> 4, c = t & 15;
        vout[((size_t)h * NPIX + b) * HD + c] = acc;
    } else if (b < NPIX + NQ) {  // ---- offsets + attention ----
        const int q = b - NPIX;
        __shared__ float qrow[EMBED];
        __shared__ float attn[32];
        qrow[t] = query[(size_t)q * EMBED + t];
        __syncthreads();
        if (t < 64) {
            float acc = boff[t];
#pragma unroll 8
            for (int k = 0; k < EMBED; ++k)
                acc = fmaf(qrow[k], Woff[(size_t)k * 64 + t], acc);
            off_out[(size_t)q * 64 + t] = acc;
        } else if (t < 96) {
            const int j = t - 64;
            float acc = battn[j];
#pragma unroll 8
            for (int k = 0; k < EMBED; ++k)
                acc = fmaf(qrow[k], Wattn[(size_t)k * 32 + j], acc);
            attn[j] = acc;
        }
        __syncthreads();
        if (t < NHEADS) {
            const float a0 = attn[t * 4 + 0], a1 = attn[t * 4 + 1];
            const float a2 = attn[t * 4 + 2], a3 = attn[t * 4 + 3];
            const float mx = fmaxf(fmaxf(a0, a1), fmaxf(a2, a3));
            const float e0 = __expf(a0 - mx), e1 = __expf(a1 - mx);
            const float e2 = __expf(a2 - mx), e3 = __expf(a3 - mx);
            const float inv = 1.f / (e0 + e1 + e2 + e3);
            aw_out[(size_t)q * 32 + t * 4 + 0] = e0 * inv;
            aw_out[(size_t)q * 32 + t * 4 + 1] = e1 * inv;
            aw_out[(size_t)q * 32 + t * 4 + 2] = e2 * inv;
            aw_out[(size_t)q * 32 + t * 4 + 3] = e3 * inv;
        }
    } else {  // ---- u = W_out @ W_proj ----
        float acc = 0.f;
#pragma unroll 8
        for (int d = 0; d < EMBED; ++d)
            acc = fmaf(Wout[(size_t)t * EMBED + d], Wproj[d], acc);
        u_out[t] = acc;
    }
}

// ---------------------------------------------------------------------------
// Main kernel. 64 lanes (one wave) per query; block=256 -> 4 queries/block.
// lane = half*32 + h*4 + c4. Half w processes levels l = 2i+w, i=0..24.
// x-axis sampling state is level-independent -> hoisted out of the loop.
// No online rescale: Z += e, acc += e*s (logits are tiny); max/argmax via
// pure selects; halves merged with shfl_xor(32) at the end.
// ---------------------------------------------------------------------------
__global__ __launch_bounds__(256) void k_main(
    const float* __restrict__ query,
    const float* __restrict__ refp,   // (NLVL, NQ, 2)
    const float* __restrict__ voff,   // (NQ, 8, 4, 2)
    const float* __restrict__ vaw,    // (NQ, 8, 4)
    const float* __restrict__ vflat,  // (8, NPIX, 16)
    const float* __restrict__ uvec,   // (128)
    const float* __restrict__ Wout,   // (128, 128)
    const float* __restrict__ bout,   // (128)
    float* __restrict__ out0,         // (NQ, 128)
    float* __restrict__ out1) {       // (NQ) argmax level, as float
    const int t = threadIdx.x;
    const int slot = t >> 6;          // query slot in block (0..3)
    const int lane = t & 63;
    const int half = lane >> 5;
    const int sub  = lane & 31;
    const int h  = sub >> 2;
    const int c4 = sub & 3;
    const int q = blockIdx.x * 4 + slot;

    __shared__ float s_rpy[4][NLVL];
    __shared__ float4 s_lds[4][32];

    // cooperative preload of ref.y for this block's 4 queries
    {
        int i = t;
        if (i < 4 * NLVL) {
            const int ql = i / NLVL, l = i - ql * NLVL;
            const int qq = blockIdx.x * 4 + ql;
            s_rpy[ql][l] = refp[((size_t)l * NQ + qq) * 2 + 1];
        }
    }

    const float4* offp = (const float4*)(voff + (size_t)q * 64 + h * 8);
    const float4 o01 = offp[0];       // p0.x p0.y p1.x p1.y
    const float4 o23 = offp[1];
    const float4 awv4 = *(const float4*)(vaw + (size_t)q * 32 + h * 4);
    const float4 u4 = *(const float4*)(uvec + h * 16 + c4 * 4);
    const float rpx = refp[(size_t)q * 2];   // level 0; col is level-invariant
    const float4* vbase = (const float4*)vflat + (size_t)h * NPIX * 4 + c4;

    const float offx[4] = {o01.x, o01.z, o23.x, o23.z};
    const float offy[4] = {o01.y, o01.w, o23.y, o23.w};
    const float awv[4]  = {awv4.x, awv4.y, awv4.z, awv4.w};

    // level-independent x-axis state per point
    float wx0[NPOINTS], wx1[NPOINTS], oyc[NPOINTS];
    int xo0[NPOINTS], xo1[NPOINTS];
#pragma unroll
    for (int p = 0; p < NPOINTS; ++p) {
        const float px = fmaf(rpx, (float)WSP, offx[p]) - 0.5f;
        const float fx = floorf(px);
        const float dx = px - fx;
        const int x0 = (int)fx, x1 = x0 + 1;
        const float a = awv[p];
        wx0[p] = ((unsigned)x0 < (unsigned)WSP) ? a * (1.f - dx) : 0.f;
        wx1[p] = ((unsigned)x1 < (unsigned)WSP) ? a * dx : 0.f;
        xo0[p] = min(max(x0, 0), WSP - 1) * 4;
        xo1[p] = min(max(x1, 0), WSP - 1) * 4;
        oyc[p] = offy[p] - 0.5f;
    }

    __syncthreads();

    float4 acc = {0.f, 0.f, 0.f, 0.f};
    float Z = 0.f, m = -1e30f;
    int best = 0;

#pragma unroll 2
    for (int i = 0; i < NLVL / 2; ++i) {
        const int l = 2 * i + half;
        const float rpy = s_rpy[slot][l];
        float4 s = {0.f, 0.f, 0.f, 0.f};
#pragma unroll
        for (int p = 0; p < NPOINTS; ++p) {
            const float py = fmaf(rpy, (float)HSP, oyc[p]);
            const float fy = floorf(py);
            const float dy = py - fy;
            const int y0 = (int)fy, y1 = y0 + 1;
            const float t0 = ((unsigned)y0 < (unsigned)HSP) ? (1.f - dy) : 0.f;
            const float t1 = ((unsigned)y1 < (unsigned)HSP) ? dy : 0.f;
            const int rb0 = min(max(y0, 0), HSP - 1) * (WSP * 4);
            const int rb1 = min(max(y1, 0), HSP - 1) * (WSP * 4);
            const float w00 = wx0[p] * t0;
            const float w01 = wx1[p] * t0;
            const float w10 = wx0[p] * t1;
            const float w11 = wx1[p] * t1;
            const float4 v00 = vbase[rb0 + xo0[p]];
            const float4 v01 = vbase[rb0 + xo1[p]];
            const float4 v10 = vbase[rb1 + xo0[p]];
            const float4 v11 = vbase[rb1 + xo1[p]];
            s.x = fmaf(w00, v00.x, s.x); s.y = fmaf(w00, v00.y, s.y);
            s.z = fmaf(w00, v00.z, s.z); s.w = fmaf(w00, v00.w, s.w);
            s.x = fmaf(w01, v01.x, s.x); s.y = fmaf(w01, v01.y, s.y);
            s.z = fmaf(w01, v01.z, s.z); s.w = fmaf(w01, v01.w, s.w);
            s.x = fmaf(w10, v10.x, s.x); s.y = fmaf(w10, v10.y, s.y);
            s.z = fmaf(w10, v10.z, s.z); s.w = fmaf(w10, v10.w, s.w);
            s.x = fmaf(w11, v11.x, s.x); s.y = fmaf(w11, v11.y, s.y);
            s.z = fmaf(w11, v11.z, s.z); s.w = fmaf(w11, v11.w, s.w);
        }
        // logit = samp_agg . u, reduced over the 32 lanes of this half
        float part = s.x * u4.x;
        part = fmaf(s.y, u4.y, part);
        part = fmaf(s.z, u4.z, part);
        part = fmaf(s.w, u4.w, part);
#pragma unroll
        for (int d = 1; d < 32; d <<= 1)
            part += __shfl_xor(part, d, 64);
        const float e = __expf(part);
        Z += e;
        acc.x = fmaf(e, s.x, acc.x);
        acc.y = fmaf(e, s.y, acc.y);
        acc.z = fmaf(e, s.z, acc.z);
        acc.w = fmaf(e, s.w, acc.w);
        best = (part > m) ? l : best;   // strict > : first occurrence wins
        m = fmaxf(part, m);
    }

    // merge the two halves (exact: plain sums, no rescale)
    {
        const float mo = __shfl_xor(m, 32, 64);
        const int   bo = __shfl_xor(best, 32, 64);
        const float Zo = __shfl_xor(Z, 32, 64);
        const float ax = __shfl_xor(acc.x, 32, 64);
        const float ay = __shfl_xor(acc.y, 32, 64);
        const float az = __shfl_xor(acc.z, 32, 64);
        const float aw_ = __shfl_xor(acc.w, 32, 64);
        const bool takeOther = (mo > m) || (mo == m && bo < best);
        best = takeOther ? bo : best;
        Z += Zo;
        acc.x += ax; acc.y += ay; acc.z += az; acc.w += aw_;
    }
    const float inv = 1.f / Z;
    if (half == 0) {
        float4 sv;
        sv.x = acc.x * inv; sv.y = acc.y * inv;
        sv.z = acc.z * inv; sv.w = acc.w * inv;
        s_lds[slot][sub] = sv;          // channel-group index == sub
        if (sub == 0) out1[q] = (float)best;
    }
    __syncthreads();

    // final: out[dp] = sum_c s[c]*Wout[c][dp] + bout[dp] + 2*query[q][dp]
    // split-K across the two halves: half0 sums cg 0..15, half1 cg 16..31
    const int dpb = sub * 4;
    float4 r = {0.f, 0.f, 0.f, 0.f};
    if (half == 0) {
        const float4 b4 = *(const float4*)(bout + dpb);
        const float4 q4 = *(const float4*)(query + (size_t)q * EMBED + dpb);
        r.x = fmaf(2.f, q4.x, b4.x);
        r.y = fmaf(2.f, q4.y, b4.y);
        r.z = fmaf(2.f, q4.z, b4.z);
        r.w = fmaf(2.f, q4.w, b4.w);
    }
    const float4* srow = s_lds[slot];
    const int cg0 = half * 16;
#pragma unroll 4
    for (int cg = cg0; cg < cg0 + 16; ++cg) {
        const float4 s4 = srow[cg];
        const float4 w0 = *(const float4*)(Wout + (size_t)(cg * 4 + 0) * EMBED + dpb);
        const float4 w1 = *(const float4*)(Wout + (size_t)(cg * 4 + 1) * EMBED + dpb);
        const float4 w2 = *(const float4*)(Wout + (size_t)(cg * 4 + 2) * EMBED + dpb);
        const float4 w3 = *(const float4*)(Wout + (size_t)(cg * 4 + 3) * EMBED + dpb);
        r.x = fmaf(s4.x, w0.x, r.x); r.y = fmaf(s4.x, w0.y, r.y);
        r.z = fmaf(s4.x, w0.z, r.z); r.w = fmaf(s4.x, w0.w, r.w);
        r.x = fmaf(s4.y, w1.x, r.x); r.y = fmaf(s4.y, w1.y, r.y);
        r.z = fmaf(s4.y, w1.z, r.z); r.w = fmaf(s4.y, w1.w, r.w);
        r.x = fmaf(s4.z, w2.x, r.x); r.y = fmaf(s4.z, w2.y, r.y);
        r.z = fmaf(s4.z, w2.z, r.z); r.w = fmaf(s4.z, w2.w, r.w);
        r.x = fmaf(s4.w, w3.x, r.x); r.y = fmaf(s4.w, w3.y, r.y);
        r.z = fmaf(s4.w, w3.z, r.z); r.w = fmaf(s4.w, w3.w, r.w);
    }
    // combine the two half-sums and store from half 0
    {
        const float rx = __shfl_xor(r.x, 32, 64);
        const float ry = __shfl_xor(r.y, 32, 64);
        const float rz = __shfl_xor(r.z, 32, 64);
        const float rw = __shfl_xor(r.w, 32, 64);
        r.x += rx; r.y += ry; r.z += rz; r.w += rw;
    }
    if (half == 0)
        *(float4*)(out0 + (size_t)q * EMBED + dpb) = r;
}

// ---------------------------------------------------------------------------
extern "C" void kernel_launch(void* const* d_in, const int* in_sizes, int n_in,
                              void* d_out, int out_size, void* d_ws, size_t ws_size,
                              hipStream_t stream) {
    const float* query = (const float*)d_in[0];
    const float* value = (const float*)d_in[1];
    const float* refp  = (const float*)d_in[2];
    const float* Woff  = (const float*)d_in[3];
    const float* boff  = (const float*)d_in[4];
    const float* Wattn = (const float*)d_in[5];
    const float* battn = (const float*)d_in[6];
    const float* Wval  = (const float*)d_in[7];
    const float* bval  = (const float*)d_in[8];
    const float* Wout  = (const float*)d_in[9];
    const float* bout  = (const float*)d_in[10];
    const float* Wproj = (const float*)d_in[11];
    // d_in[12] = b_proj: level-constant -> cancels in softmax/argmax, unused.

    float* ws = (float*)d_ws;
    float* ws_v   = ws;                                   // 8*5202*16
    float* ws_off = ws_v + (size_t)NHEADS * NPIX * HD;    // NQ*64
    float* ws_aw  = ws_off + (size_t)NQ * 64;             // NQ*32
    float* ws_u   = ws_aw + (size_t)NQ * 32;              // 128

    float* out0 = (float*)d_out;
    float* out1 = out0 + (size_t)NQ * EMBED;

    hipLaunchKernelGGL(k_prep, dim3(NPIX + NQ + 1), dim3(128), 0, stream,
                       value, Wval, bval, query, Woff, boff, Wattn, battn,
                       Wout, Wproj, ws_v, ws_off, ws_aw, ws_u);
    hipLaunchKernelGGL(k_main, dim3(NQ / 4), dim3(256), 0, stream,
                       query, refp, ws_off, ws_aw, ws_v, ws_u, Wout, bout,
                       out0, out1);
}

// Round 4
// 253.054 us; speedup vs baseline: 1.1038x; 1.0022x over previous
//
#include <hip/hip_runtime.h>
#include <math.h>

#define EMBED   128
#define NHEADS  8
#define NPOINTS 4
#define HD      16
#define HSP     51
#define WSP     102
#define NPIX    (HSP * WSP)   // 5202
#define NQ      10000
#define NLVL    50

// ---------------------------------------------------------------------------
// Fused prep kernel. 256 threads per block, two work units per block:
//   blocks [0, 2601)            : value projection (2 pixels/block)
//   blocks [2601, 2601+5000)    : offsets + attention softmax (2 queries/block)
//   block  2601+5000            : u = W_out @ W_proj
// ---------------------------------------------------------------------------
#define NPB_A ((NPIX + 1) / 2)   // 2601
#define NPB_B (NQ / 2)           // 5000

__global__ __launch_bounds__(256) void k_prep(
    const float* __restrict__ value,
    const float* __restrict__ Wv,
    const float* __restrict__ bv,
    const float* __restrict__ query,
    const float* __restrict__ Woff,
    const float* __restrict__ boff,
    const float* __restrict__ Wattn,
    const float* __restrict__ battn,
    const float* __restrict__ Wout,
    const float* __restrict__ Wproj,
    float* __restrict__ vout,
    float* __restrict__ off_out,
    float* __restrict__ aw_out,
    float* __restrict__ u_out) {
    const int b = blockIdx.x;
    const int t = threadIdx.x;
    const int unit = t >> 7;      // 0 or 1
    const int tt = t & 127;

    if (b < NPB_A) {  // ---- value projection ----
        __shared__ float vrow[2][EMBED];
        const int pix = b * 2 + unit;
        vrow[unit][tt] = value[(size_t)pix * EMBED + tt];
        __syncthreads();
        float acc = bv[tt];
        const float* vr = vrow[unit];
#pragma unroll 8
        for (int k = 0; k < EMBED; ++k)
            acc = fmaf(vr[k], Wv[(size_t)k * EMBED + tt], acc);
        const int h = tt >> 4, c = tt & 15;
        vout[((size_t)h * NPIX + pix) * HD + c] = acc;
    } else if (b < NPB_A + NPB_B) {  // ---- offsets + attention ----
        const int q = (b - NPB_A) * 2 + unit;
        __shared__ float qrow[2][EMBED];
        __shared__ float attn[2][32];
        qrow[unit][tt] = query[(size_t)q * EMBED + tt];
        __syncthreads();
        const float* qr = qrow[unit];
        if (tt < 64) {
            float acc = boff[tt];
#pragma unroll 8
            for (int k = 0; k < EMBED; ++k)
                acc = fmaf(qr[k], Woff[(size_t)k * 64 + tt], acc);
            off_out[(size_t)q * 64 + tt] = acc;
        } else if (tt < 96) {
            const int j = tt - 64;
            float acc = battn[j];
#pragma unroll 8
            for (int k = 0; k < EMBED; ++k)
                acc = fmaf(qr[k], Wattn[(size_t)k * 32 + j], acc);
            attn[unit][j] = acc;
        }
        __syncthreads();
        if (tt < NHEADS) {
            const float a0 = attn[unit][tt * 4 + 0], a1 = attn[unit][tt * 4 + 1];
            const float a2 = attn[unit][tt * 4 + 2], a3 = attn[unit][tt * 4 + 3];
            const float mx = fmaxf(fmaxf(a0, a1), fmaxf(a2, a3));
            const float e0 = __expf(a0 - mx), e1 = __expf(a1 - mx);
            const float e2 = __expf(a2 - mx), e3 = __expf(a3 - mx);
            const float inv = 1.f / (e0 + e1 + e2 + e3);
            aw_out[(size_t)q * 32 + tt * 4 + 0] = e0 * inv;
            aw_out[(size_t)q * 32 + tt * 4 + 1] = e1 * inv;
            aw_out[(size_t)q * 32 + tt * 4 + 2] = e2 * inv;
            aw_out[(size_t)q * 32 + tt * 4 + 3] = e3 * inv;
        }
    } else {  // ---- u = W_out @ W_proj ----
        if (unit == 0) {
            float acc = 0.f;
#pragma unroll 8
            for (int d = 0; d < EMBED; ++d)
                acc = fmaf(Wout[(size_t)tt * EMBED + d], Wproj[d], acc);
            u_out[tt] = acc;
        }
    }
}

// ---------------------------------------------------------------------------
// Main kernel. 2 waves per query (levels 4-way interleaved), 2 queries per
// 256-thread block. Within a wave, the two 32-lane halves handle 2 levels per
// iteration; lane sub = h*4 + c4 owns 4 channels of head h. Cross-wave merge
// of (acc, Z, m, best) via LDS; wave 0 runs the epilogue.
// NOTE: the half-merge MUST also merge m (m = fmaxf(m, mo)) — the cross-wave
// merge consumes m as the comparison key (round-3 bug).
// ---------------------------------------------------------------------------
__global__ __launch_bounds__(256, 6) void k_main(
    const float* __restrict__ query,
    const float* __restrict__ refp,   // (NLVL, NQ, 2)
    const float* __restrict__ voff,   // (NQ, 8, 4, 2)
    const float* __restrict__ vaw,    // (NQ, 8, 4)
    const float* __restrict__ vflat,  // (8, NPIX, 16)
    const float* __restrict__ uvec,   // (128)
    const float* __restrict__ Wout,   // (128, 128)
    const float* __restrict__ bout,   // (128)
    float* __restrict__ out0,         // (NQ, 128)
    float* __restrict__ out1) {       // (NQ) argmax level, as float
    const int t = threadIdx.x;
    const int qslot = t >> 7;         // 0..1
    const int w2 = (t >> 6) & 1;      // wave index within query
    const int half = (t >> 5) & 1;
    const int sub = t & 31;
    const int h  = sub >> 2;
    const int c4 = sub & 3;
    const int q = blockIdx.x * 2 + qslot;

    __shared__ float  s_rpy[2][NLVL];
    __shared__ float4 s_acc[2][32];
    __shared__ float  s_z[2], s_m[2];
    __shared__ int    s_b[2];

    // cooperative preload of ref.y for this block's 2 queries
    if (t < 2 * NLVL) {
        const int ql = t / NLVL, l = t - ql * NLVL;
        const int qq = blockIdx.x * 2 + ql;
        s_rpy[ql][l] = refp[((size_t)l * NQ + qq) * 2 + 1];
    }

    const float4* offp = (const float4*)(voff + (size_t)q * 64 + h * 8);
    const float4 o01 = offp[0];       // p0.x p0.y p1.x p1.y
    const float4 o23 = offp[1];
    const float4 awv4 = *(const float4*)(vaw + (size_t)q * 32 + h * 4);
    const float4 u4 = *(const float4*)(uvec + h * 16 + c4 * 4);
    const float rpx = refp[(size_t)q * 2];   // col is level-invariant
    const float4* vbase = (const float4*)vflat + (size_t)h * NPIX * 4 + c4;

    const float offx[4] = {o01.x, o01.z, o23.x, o23.z};
    const float offy[4] = {o01.y, o01.w, o23.y, o23.w};
    const float awv[4]  = {awv4.x, awv4.y, awv4.z, awv4.w};

    // level-independent x-axis state per point
    float wx0[NPOINTS], wx1[NPOINTS], oyc[NPOINTS];
    int xo0[NPOINTS], xo1[NPOINTS];
#pragma unroll
    for (int p = 0; p < NPOINTS; ++p) {
        const float px = fmaf(rpx, (float)WSP, offx[p]) - 0.5f;
        const float fx = floorf(px);
        const float dx = px - fx;
        const int x0 = (int)fx, x1 = x0 + 1;
        const float a = awv[p];
        wx0[p] = ((unsigned)x0 < (unsigned)WSP) ? a * (1.f - dx) : 0.f;
        wx1[p] = ((unsigned)x1 < (unsigned)WSP) ? a * dx : 0.f;
        xo0[p] = min(max(x0, 0), WSP - 1) * 4;
        xo1[p] = min(max(x1, 0), WSP - 1) * 4;
        oyc[p] = offy[p] - 0.5f;
    }

    __syncthreads();

    float4 acc = {0.f, 0.f, 0.f, 0.f};
    float Z = 0.f, m = -1e30f;
    int best = 0;

#pragma unroll 1
    for (int i = 0; i < 13; ++i) {
        if (4 * i + (w2 << 1) >= NLVL) break;   // wave-uniform (depends on w2 only)
        const int l = 4 * i + (w2 << 1) + half;
        const float rpy = s_rpy[qslot][l];
        float4 s = {0.f, 0.f, 0.f, 0.f};
#pragma unroll
        for (int p = 0; p < NPOINTS; ++p) {
            const float py = fmaf(rpy, (float)HSP, oyc[p]);
            const float fy = floorf(py);
            const float dy = py - fy;
            const int y0 = (int)fy, y1 = y0 + 1;
            const float t0 = ((unsigned)y0 < (unsigned)HSP) ? (1.f - dy) : 0.f;
            const float t1 = ((unsigned)y1 < (unsigned)HSP) ? dy : 0.f;
            const int rb0 = min(max(y0, 0), HSP - 1) * (WSP * 4);
            const int rb1 = min(max(y1, 0), HSP - 1) * (WSP * 4);
            const float w00 = wx0[p] * t0;
            const float w01 = wx1[p] * t0;
            const float w10 = wx0[p] * t1;
            const float w11 = wx1[p] * t1;
            const float4 v00 = vbase[rb0 + xo0[p]];
            const float4 v01 = vbase[rb0 + xo1[p]];
            const float4 v10 = vbase[rb1 + xo0[p]];
            const float4 v11 = vbase[rb1 + xo1[p]];
            s.x = fmaf(w00, v00.x, s.x); s.y = fmaf(w00, v00.y, s.y);
            s.z = fmaf(w00, v00.z, s.z); s.w = fmaf(w00, v00.w, s.w);
            s.x = fmaf(w01, v01.x, s.x); s.y = fmaf(w01, v01.y, s.y);
            s.z = fmaf(w01, v01.z, s.z); s.w = fmaf(w01, v01.w, s.w);
            s.x = fmaf(w10, v10.x, s.x); s.y = fmaf(w10, v10.y, s.y);
            s.z = fmaf(w10, v10.z, s.z); s.w = fmaf(w10, v10.w, s.w);
            s.x = fmaf(w11, v11.x, s.x); s.y = fmaf(w11, v11.y, s.y);
            s.z = fmaf(w11, v11.z, s.z); s.w = fmaf(w11, v11.w, s.w);
        }
        // logit = samp_agg . u, reduced over the 32 lanes of this half
        float part = s.x * u4.x;
        part = fmaf(s.y, u4.y, part);
        part = fmaf(s.z, u4.z, part);
        part = fmaf(s.w, u4.w, part);
#pragma unroll
        for (int d = 1; d < 32; d <<= 1)
            part += __shfl_xor(part, d, 64);
        const float e = __expf(part);
        Z += e;
        acc.x = fmaf(e, s.x, acc.x);
        acc.y = fmaf(e, s.y, acc.y);
        acc.z = fmaf(e, s.z, acc.z);
        acc.w = fmaf(e, s.w, acc.w);
        best = (part > m) ? l : best;   // strict > : first occurrence wins
        m = fmaxf(part, m);
    }

    // merge the two halves of this wave (exact: plain sums, no rescale)
    {
        const float mo = __shfl_xor(m, 32, 64);
        const int   bo = __shfl_xor(best, 32, 64);
        const float Zo = __shfl_xor(Z, 32, 64);
        const float ax = __shfl_xor(acc.x, 32, 64);
        const float ay = __shfl_xor(acc.y, 32, 64);
        const float az = __shfl_xor(acc.z, 32, 64);
        const float aw_ = __shfl_xor(acc.w, 32, 64);
        const bool takeOther = (mo > m) || (mo == m && bo < best);
        best = takeOther ? bo : best;
        m = fmaxf(m, mo);               // <- the round-3 fix: merge the key too
        Z += Zo;
        acc.x += ax; acc.y += ay; acc.z += az; acc.w += aw_;
    }

    // wave 1 publishes its partials; wave 0 merges and finishes
    if (w2 == 1) {
        if (half == 0) s_acc[qslot][sub] = acc;
        if ((t & 63) == 0) { s_z[qslot] = Z; s_m[qslot] = m; s_b[qslot] = best; }
    }
    __syncthreads();

    if (w2 == 0) {
        const float4 ao = s_acc[qslot][sub];
        const float Zo = s_z[qslot];
        const float mo = s_m[qslot];
        const int   bo = s_b[qslot];
        const bool takeOther = (mo > m) || (mo == m && bo < best);
        best = takeOther ? bo : best;
        Z += Zo;
        acc.x += ao.x; acc.y += ao.y; acc.z += ao.z; acc.w += ao.w;

        const float inv = 1.f / Z;
        if (half == 0) {
            float4 sv;
            sv.x = acc.x * inv; sv.y = acc.y * inv;
            sv.z = acc.z * inv; sv.w = acc.w * inv;
            s_acc[qslot][sub] = sv;       // channel-group index == sub
            if (sub == 0) out1[q] = (float)best;
        }
        // same-wave DS ordering makes the write visible to both halves below

        // final: out[dp] = sum_c s[c]*Wout[c][dp] + bout[dp] + 2*query[q][dp]
        // split-K across the two halves: half0 sums cg 0..15, half1 cg 16..31
        const int dpb = sub * 4;
        float4 r = {0.f, 0.f, 0.f, 0.f};
        if (half == 0) {
            const float4 b4 = *(const float4*)(bout + dpb);
            const float4 q4 = *(const float4*)(query + (size_t)q * EMBED + dpb);
            r.x = fmaf(2.f, q4.x, b4.x);
            r.y = fmaf(2.f, q4.y, b4.y);
            r.z = fmaf(2.f, q4.z, b4.z);
            r.w = fmaf(2.f, q4.w, b4.w);
        }
        const float4* srow = s_acc[qslot];
        const int cg0 = half * 16;
#pragma unroll 4
        for (int cg = cg0; cg < cg0 + 16; ++cg) {
            const float4 s4 = srow[cg];
            const float4 w0 = *(const float4*)(Wout + (size_t)(cg * 4 + 0) * EMBED + dpb);
            const float4 w1 = *(const float4*)(Wout + (size_t)(cg * 4 + 1) * EMBED + dpb);
            const float4 w2v = *(const float4*)(Wout + (size_t)(cg * 4 + 2) * EMBED + dpb);
            const float4 w3 = *(const float4*)(Wout + (size_t)(cg * 4 + 3) * EMBED + dpb);
            r.x = fmaf(s4.x, w0.x, r.x); r.y = fmaf(s4.x, w0.y, r.y);
            r.z = fmaf(s4.x, w0.z, r.z); r.w = fmaf(s4.x, w0.w, r.w);
            r.x = fmaf(s4.y, w1.x, r.x); r.y = fmaf(s4.y, w1.y, r.y);
            r.z = fmaf(s4.y, w1.z, r.z); r.w = fmaf(s4.y, w1.w, r.w);
            r.x = fmaf(s4.z, w2v.x, r.x); r.y = fmaf(s4.z, w2v.y, r.y);
            r.z = fmaf(s4.z, w2v.z, r.z); r.w = fmaf(s4.z, w2v.w, r.w);
            r.x = fmaf(s4.w, w3.x, r.x); r.y = fmaf(s4.w, w3.y, r.y);
            r.z = fmaf(s4.w, w3.z, r.z); r.w = fmaf(s4.w, w3.w, r.w);
        }
        // combine the two half-sums and store from half 0
        {
            const float rx = __shfl_xor(r.x, 32, 64);
            const float ry = __shfl_xor(r.y, 32, 64);
            const float rz = __shfl_xor(r.z, 32, 64);
            const float rw = __shfl_xor(r.w, 32, 64);
            r.x += rx; r.y += ry; r.z += rz; r.w += rw;
        }
        if (half == 0)
            *(float4*)(out0 + (size_t)q * EMBED + dpb) = r;
    }
}

// ---------------------------------------------------------------------------
extern "C" void kernel_launch(void* const* d_in, const int* in_sizes, int n_in,
                              void* d_out, int out_size, void* d_ws, size_t ws_size,
                              hipStream_t stream) {
    const float* query = (const float*)d_in[0];
    const float* value = (const float*)d_in[1];
    const float* refp  = (const float*)d_in[2];
    const float* Woff  = (const float*)d_in[3];
    const float* boff  = (const float*)d_in[4];
    const float* Wattn = (const float*)d_in[5];
    const float* battn = (const float*)d_in[6];
    const float* Wval  = (const float*)d_in[7];
    const float* bval  = (const float*)d_in[8];
    const float* Wout  = (const float*)d_in[9];
    const float* bout  = (const float*)d_in[10];
    const float* Wproj = (const float*)d_in[11];
    // d_in[12] = b_proj: level-constant -> cancels in softmax/argmax, unused.

    float* ws = (float*)d_ws;
    float* ws_v   = ws;                                   // 8*5202*16
    float* ws_off = ws_v + (size_t)NHEADS * NPIX * HD;    // NQ*64
    float* ws_aw  = ws_off + (size_t)NQ * 64;             // NQ*32
    float* ws_u   = ws_aw + (size_t)NQ * 32;              // 128

    float* out0 = (float*)d_out;
    float* out1 = out0 + (size_t)NQ * EMBED;

    hipLaunchKernelGGL(k_prep, dim3(NPB_A + NPB_B + 1), dim3(256), 0, stream,
                       value, Wval, bval, query, Woff, boff, Wattn, battn,
                       Wout, Wproj, ws_v, ws_off, ws_aw, ws_u);
    hipLaunchKernelGGL(k_main, dim3(NQ / 2), dim3(256), 0, stream,
                       query, refp, ws_off, ws_aw, ws_v, ws_u, Wout, bout,
                       out0, out1);
}